// Round 10
// baseline (536.480 us; speedup 1.0000x reference)
//
#include <hip/hip_runtime.h>
#include <hip/hip_cooperative_groups.h>

namespace cg = cooperative_groups;

#define N 1024
#define NUM_IN 2048
#define NE (N * N)              // 1048576 elements of W_rec
#define TAU 20.0f
#define LR 0.001f
#define CHUNKS 64
#define RPC 48                  // rows per chunk: 64*48 = 3072 reduction rows

typedef float f4 __attribute__((ext_vector_type(4)));

// ======================= FUSED cooperative kernel ===========================
// Phase A: all blocks issue iter-0 pW2 loads (saturate HBM from t=0).
// Phase B: blocks 0..255 compute stage-1 partials (overlapped). grid.sync.
// Phase C: blocks 0..63 finish LIF + MLP1 -> h. grid.sync.
// Phase D: all blocks run the policy GEMV+plasticity stream (r7 structure,
//          4 consecutive elems / 16-lane group, 2-deep pipeline, all-nt).
#define GGRID 1024
#define GITERS 16
#define GESTRIDE (GGRID * 4 * 16)                // 65536 elements per iter

__global__ __launch_bounds__(256, 4) void fused_all(
    const float* __restrict__ in_spk, const float* __restrict__ prev_spk,
    const float* __restrict__ potential, const float* __restrict__ W_in,
    const float* __restrict__ W_rec, const float* __restrict__ pW1,
    const float* __restrict__ pb1, const float* __restrict__ pW2,
    const float* __restrict__ pb2, float* __restrict__ out_spk,
    float* __restrict__ out_rec, float* __restrict__ partial,
    float* __restrict__ h_ws) {
    cg::grid_group grid = cg::this_grid();
    __shared__ float spk[RPC];
    __shared__ float comb[2 * N];
    __shared__ float red[256];

    const int t = threadIdx.x;
    const int lane = t & 63;
    const int wave = t >> 6;
    const int group = lane >> 4;
    const int sub = lane & 15;
    const int gw = blockIdx.x * 4 + wave;        // 4096 waves
    const int e0 = gw * 16 + group * 4;          // group's 4 consecutive elems
    const f4* pr = (const f4*)pW2 + (size_t)e0 * 16 + sub;
    const f4* gr = (const f4*)pW2 + ((size_t)NE + e0) * 16 + sub;
    const size_t FSTR = (size_t)GESTRIDE * 16;   // f4 stride per iteration

    // ---- Phase A: issue iteration-0 policy loads (no h dependence) ----
    f4 pA[4], gA[4];
    #pragma unroll
    for (int m = 0; m < 4; ++m) {
        pA[m] = __builtin_nontemporal_load(pr + m * 16);
        gA[m] = __builtin_nontemporal_load(gr + m * 16);
    }

    // ---- Phase B: stage-1 partial sums (blocks 0..255) ----
    if (blockIdx.x < 256) {
        int jg = blockIdx.x & 3;
        int ic = blockIdx.x >> 2;
        int j = jg * 256 + t;
        int r0 = ic * RPC;
        if (t < RPC) {
            int r = r0 + t;
            spk[t] = (r < NUM_IN) ? in_spk[r] : prev_spk[r - NUM_IN];
        }
        __syncthreads();
        float acc = 0.f;
        #pragma unroll 4
        for (int u = 0; u < RPC; ++u) {
            int r = r0 + u;
            float s = spk[u];
            if (s != 0.f) {
                const float* Wrow = (r < NUM_IN) ? (W_in + (size_t)r * N)
                                                 : (W_rec + (size_t)(r - NUM_IN) * N);
                acc = fmaf(s, Wrow[j], acc);
            }
        }
        partial[ic * N + j] = acc;
    }
    __threadfence();
    grid.sync();

    // ---- Phase C: LIF finish + MLP1 (blocks 0..63) ----
    if (blockIdx.x < 64) {
        #pragma unroll
        for (int n0 = 0; n0 < N; n0 += 256) {
            int j = n0 + t;
            float tc = 0.f;
            #pragma unroll 8
            for (int ic = 0; ic < CHUNKS; ++ic) tc += partial[ic * N + j];
            float p = potential[j];
            float v = p + (-p / TAU + tc);       // DT = 1
            float s = (v >= 1.0f) ? 1.f : 0.f;
            comb[j] = prev_spk[j];
            comb[N + j] = s;
            if (blockIdx.x == 0) out_spk[j] = s;
        }
        __syncthreads();
        const float* row = pW1 + (size_t)blockIdx.x * (2 * N);
        float acc = 0.f;
        #pragma unroll
        for (int u = 0; u < 8; ++u) {
            int j = u * 256 + t;
            acc = fmaf(comb[j], row[j], acc);
        }
        red[t] = acc;
        __syncthreads();
        for (int s2 = 128; s2 > 0; s2 >>= 1) {
            if (t < s2) red[t] += red[t + s2];
            __syncthreads();
        }
        if (t == 0) h_ws[blockIdx.x] = fmaxf(red[0] + pb1[blockIdx.x], 0.f);
    }
    __threadfence();
    grid.sync();

    // ---- Phase D: policy stream ----
    f4 hv = ((const f4*)h_ws)[sub];              // h[4*sub .. 4*sub+3]
    for (int it = 0; it < GITERS; ++it) {
        // issue NEXT iteration's loads first (stay in flight during compute)
        f4 pN[4] = {}, gN[4] = {};
        if (it + 1 < GITERS) {
            const f4* prn = pr + (size_t)(it + 1) * FSTR;
            const f4* grn = gr + (size_t)(it + 1) * FSTR;
            #pragma unroll
            for (int m = 0; m < 4; ++m) {
                pN[m] = __builtin_nontemporal_load(prn + m * 16);
                gN[m] = __builtin_nontemporal_load(grn + m * 16);
            }
        }
        int e = e0 + it * GESTRIDE;
        f4 bp{}, bg{}, wv{};
        if (sub == 0) {                          // side loads, non-pipelined
            bp = *(const f4*)(pb2 + e);
            bg = *(const f4*)(pb2 + NE + e);
            wv = *(const f4*)(W_rec + e);
        }
        float sp[4], sg[4];
        #pragma unroll
        for (int m = 0; m < 4; ++m) {
            sp[m] = pA[m].x * hv.x + pA[m].y * hv.y + pA[m].z * hv.z + pA[m].w * hv.w;
            sg[m] = gA[m].x * hv.x + gA[m].y * hv.y + gA[m].z * hv.z + gA[m].w * hv.w;
        }
        #pragma unroll
        for (int off = 1; off < 16; off <<= 1) {
            #pragma unroll
            for (int m = 0; m < 4; ++m) {
                sp[m] += __shfl_xor(sp[m], off);
                sg[m] += __shfl_xor(sg[m], off);
            }
        }
        if (sub == 0) {
            f4 res;
            #pragma unroll
            for (int m = 0; m < 4; ++m) {
                float sig_p = 1.f / (1.f + __expf(-(sp[m] + bp[m])));
                float sig_g = 1.f / (1.f + __expf(-(sg[m] + bg[m])));
                float nw = fmaxf(wv[m] - LR * sig_p + LR * sig_g, 0.f);
                int em = e + m;
                int r = em >> 10, c = em & (N - 1);
                res[m] = (r == c) ? 0.f : nw;
            }
            *(f4*)(out_rec + e) = res;
        }
        #pragma unroll
        for (int m = 0; m < 4; ++m) { pA[m] = pN[m]; gA[m] = gN[m]; }
    }
}

// ================== Fallback: round-7 three-kernel path =====================
__global__ __launch_bounds__(256) void lif_partial(
    const float* __restrict__ in_spk, const float* __restrict__ prev_spk,
    const float* __restrict__ W_in, const float* __restrict__ W_rec,
    float* __restrict__ partial) {
    __shared__ float spk[RPC];
    int jg = blockIdx.x & 3;
    int ic = blockIdx.x >> 2;
    int j = jg * 256 + threadIdx.x;
    int r0 = ic * RPC;
    if (threadIdx.x < RPC) {
        int r = r0 + threadIdx.x;
        spk[threadIdx.x] = (r < NUM_IN) ? in_spk[r] : prev_spk[r - NUM_IN];
    }
    __syncthreads();
    float acc = 0.f;
    #pragma unroll 4
    for (int u = 0; u < RPC; ++u) {
        int r = r0 + u;
        float s = spk[u];
        if (s != 0.f) {
            const float* Wrow = (r < NUM_IN) ? (W_in + (size_t)r * N)
                                             : (W_rec + (size_t)(r - NUM_IN) * N);
            acc = fmaf(s, Wrow[j], acc);
        }
    }
    partial[ic * N + j] = acc;
}

__global__ __launch_bounds__(256) void finish_mlp1(
    const float* __restrict__ partial, const float* __restrict__ potential,
    const float* __restrict__ prev_spk, const float* __restrict__ pW1,
    const float* __restrict__ pb1, float* __restrict__ out_spk,
    float* __restrict__ h) {
    __shared__ float comb[2 * N];
    __shared__ float red[256];
    int t = threadIdx.x;
    #pragma unroll
    for (int n0 = 0; n0 < N; n0 += 256) {
        int j = n0 + t;
        float tc = 0.f;
        #pragma unroll 8
        for (int ic = 0; ic < CHUNKS; ++ic) tc += partial[ic * N + j];
        float p = potential[j];
        float v = p + (-p / TAU + tc);           // DT = 1
        float s = (v >= 1.0f) ? 1.f : 0.f;
        comb[j] = prev_spk[j];
        comb[N + j] = s;
        if (blockIdx.x == 0) out_spk[j] = s;
    }
    __syncthreads();
    const float* row = pW1 + (size_t)blockIdx.x * (2 * N);
    float acc = 0.f;
    #pragma unroll
    for (int u = 0; u < 8; ++u) {
        int j = u * 256 + t;
        acc = fmaf(comb[j], row[j], acc);
    }
    red[t] = acc;
    __syncthreads();
    for (int s = 128; s > 0; s >>= 1) {
        if (t < s) red[t] += red[t + s];
        __syncthreads();
    }
    if (t == 0) h[blockIdx.x] = fmaxf(red[0] + pb1[blockIdx.x], 0.f);
}

#define PITERS 8
#define PESTRIDE (8192 * 16)
__global__ __launch_bounds__(256) void policy_update(
    const float* __restrict__ pW2, const float* __restrict__ pb2,
    const float* __restrict__ W_rec, const float* __restrict__ h,
    float* __restrict__ out_rec) {
    int lane = threadIdx.x & 63;
    int wave = threadIdx.x >> 6;
    int group = lane >> 4;
    int sub = lane & 15;
    int gw = blockIdx.x * 4 + wave;
    f4 hv = ((const f4*)h)[sub];
    int e0 = gw * 16 + group * 4;
    const f4* pr = (const f4*)pW2 + (size_t)e0 * 16 + sub;
    const f4* gr = (const f4*)pW2 + ((size_t)NE + e0) * 16 + sub;
    const size_t FSTR = (size_t)PESTRIDE * 16;

    f4 pA[4], gA[4];
    #pragma unroll
    for (int m = 0; m < 4; ++m) {
        pA[m] = __builtin_nontemporal_load(pr + m * 16);
        gA[m] = __builtin_nontemporal_load(gr + m * 16);
    }
    f4 bp{}, bg{}, wv{};
    if (sub == 0) {
        bp = *(const f4*)(pb2 + e0);
        bg = *(const f4*)(pb2 + NE + e0);
        wv = *(const f4*)(W_rec + e0);
    }
    for (int it = 0; it < PITERS; ++it) {
        f4 pN[4] = {}, gN[4] = {};
        f4 bpn{}, bgn{}, wvn{};
        if (it + 1 < PITERS) {
            const f4* prn = pr + (size_t)(it + 1) * FSTR;
            const f4* grn = gr + (size_t)(it + 1) * FSTR;
            #pragma unroll
            for (int m = 0; m < 4; ++m) {
                pN[m] = __builtin_nontemporal_load(prn + m * 16);
                gN[m] = __builtin_nontemporal_load(grn + m * 16);
            }
            if (sub == 0) {
                int en = e0 + (it + 1) * PESTRIDE;
                bpn = *(const f4*)(pb2 + en);
                bgn = *(const f4*)(pb2 + NE + en);
                wvn = *(const f4*)(W_rec + en);
            }
        }
        float sp[4], sg[4];
        #pragma unroll
        for (int m = 0; m < 4; ++m) {
            sp[m] = pA[m].x * hv.x + pA[m].y * hv.y + pA[m].z * hv.z + pA[m].w * hv.w;
            sg[m] = gA[m].x * hv.x + gA[m].y * hv.y + gA[m].z * hv.z + gA[m].w * hv.w;
        }
        #pragma unroll
        for (int off = 1; off < 16; off <<= 1) {
            #pragma unroll
            for (int m = 0; m < 4; ++m) {
                sp[m] += __shfl_xor(sp[m], off);
                sg[m] += __shfl_xor(sg[m], off);
            }
        }
        if (sub == 0) {
            int e = e0 + it * PESTRIDE;
            f4 res;
            #pragma unroll
            for (int m = 0; m < 4; ++m) {
                float sig_p = 1.f / (1.f + __expf(-(sp[m] + bp[m])));
                float sig_g = 1.f / (1.f + __expf(-(sg[m] + bg[m])));
                float nw = fmaxf(wv[m] - LR * sig_p + LR * sig_g, 0.f);
                int em = e + m;
                int r = em >> 10, c = em & (N - 1);
                res[m] = (r == c) ? 0.f : nw;
            }
            *(f4*)(out_rec + e) = res;
        }
        #pragma unroll
        for (int m = 0; m < 4; ++m) { pA[m] = pN[m]; gA[m] = gN[m]; }
        bp = bpn; bg = bgn; wv = wvn;
    }
}

extern "C" void kernel_launch(void* const* d_in, const int* in_sizes, int n_in,
                              void* d_out, int out_size, void* d_ws, size_t ws_size,
                              hipStream_t stream) {
    const float* in_spk    = (const float*)d_in[0];
    const float* prev_spk  = (const float*)d_in[1];
    const float* potential = (const float*)d_in[2];
    const float* W_in      = (const float*)d_in[3];
    const float* W_rec     = (const float*)d_in[4];
    const float* pW1       = (const float*)d_in[5];
    const float* pb1       = (const float*)d_in[6];
    const float* pW2       = (const float*)d_in[7];
    const float* pb2       = (const float*)d_in[8];
    float* out     = (float*)d_out;              // [0,1024): spikes
    float* out_rec = out + N;                    // then new W_rec
    float* ws      = (float*)d_ws;
    float* partial = ws;                         // 64*1024 floats
    float* h       = ws + CHUNKS * N;            // 64 floats (16B-aligned)

    void* args[] = {
        (void*)&in_spk, (void*)&prev_spk, (void*)&potential, (void*)&W_in,
        (void*)&W_rec, (void*)&pW1, (void*)&pb1, (void*)&pW2, (void*)&pb2,
        (void*)&out, (void*)&out_rec, (void*)&partial, (void*)&h,
    };
    hipError_t err = hipLaunchCooperativeKernel(
        (const void*)fused_all, dim3(GGRID), dim3(256), args, 0, stream);
    if (err != hipSuccess) {
        // Fallback: round-7 three-kernel path (best-known 112.5 us config)
        lif_partial<<<256, 256, 0, stream>>>(in_spk, prev_spk, W_in, W_rec, partial);
        finish_mlp1<<<64, 256, 0, stream>>>(partial, potential, prev_spk, pW1, pb1, out, h);
        policy_update<<<2048, 256, 0, stream>>>(pW2, pb2, W_rec, h, out_rec);
    }
}

// Round 11
// 111.897 us; speedup vs baseline: 4.7944x; 4.7944x over previous
//
#include <hip/hip_runtime.h>

#define N 1024
#define NUM_IN 2048
#define NE (N * N)              // 1048576 elements of W_rec
#define TAU 20.0f
#define LR 0.001f
#define CHUNKS 64
#define RPC 48                  // rows per chunk: 64*48 = 3072 reduction rows

typedef float f4 __attribute__((ext_vector_type(4)));

// ---------------- Stage 1: partial sums of total_current --------------------
// (round-3 version: wave-uniform skip branch, ~2.4 MB effective traffic)
__global__ __launch_bounds__(256) void lif_partial(
    const float* __restrict__ in_spk, const float* __restrict__ prev_spk,
    const float* __restrict__ W_in, const float* __restrict__ W_rec,
    float* __restrict__ partial) {
    __shared__ float spk[RPC];
    int jg = blockIdx.x & 3;
    int ic = blockIdx.x >> 2;
    int j = jg * 256 + threadIdx.x;
    int r0 = ic * RPC;
    if (threadIdx.x < RPC) {
        int r = r0 + threadIdx.x;
        spk[threadIdx.x] = (r < NUM_IN) ? in_spk[r] : prev_spk[r - NUM_IN];
    }
    __syncthreads();
    float acc = 0.f;
    #pragma unroll 4
    for (int u = 0; u < RPC; ++u) {
        int r = r0 + u;
        float s = spk[u];
        if (s != 0.f) {
            const float* Wrow = (r < NUM_IN) ? (W_in + (size_t)r * N)
                                             : (W_rec + (size_t)(r - NUM_IN) * N);
            acc = fmaf(s, Wrow[j], acc);
        }
    }
    partial[ic * N + j] = acc;
}

// ---------------- Stage 2: finish LIF + h = relu(combined @ pW1^T + pb1) ----
__global__ __launch_bounds__(256) void finish_mlp1(
    const float* __restrict__ partial, const float* __restrict__ potential,
    const float* __restrict__ prev_spk, const float* __restrict__ pW1,
    const float* __restrict__ pb1, float* __restrict__ out_spk,
    float* __restrict__ h) {
    __shared__ float comb[2 * N];
    __shared__ float red[256];
    int t = threadIdx.x;
    #pragma unroll
    for (int n0 = 0; n0 < N; n0 += 256) {
        int j = n0 + t;
        float tc = 0.f;
        #pragma unroll 8
        for (int ic = 0; ic < CHUNKS; ++ic) tc += partial[ic * N + j];
        float p = potential[j];
        float v = p + (-p / TAU + tc);           // DT = 1
        float s = (v >= 1.0f) ? 1.f : 0.f;
        comb[j] = prev_spk[j];
        comb[N + j] = s;
        if (blockIdx.x == 0) out_spk[j] = s;
    }
    __syncthreads();
    const float* row = pW1 + (size_t)blockIdx.x * (2 * N);
    float acc = 0.f;
    #pragma unroll
    for (int u = 0; u < 8; ++u) {
        int j = u * 256 + t;
        acc = fmaf(comb[j], row[j], acc);
    }
    red[t] = acc;
    __syncthreads();
    for (int s = 128; s > 0; s >>= 1) {
        if (t < s) red[t] += red[t + s];
        __syncthreads();
    }
    if (t == 0) h[blockIdx.x] = fmaxf(red[0] + pb1[blockIdx.x], 0.f);
}

// ---------------- Stage 3: fused policy GEMV + sigmoid + plasticity ---------
// Round-7 structure verbatim (best measured: 112.5us): 4 consecutive elements
// per 16-lane group, 8KB/wave/iter, 2-deep pipeline, RESIT plain/nt split.
// Delta this round: pb2 side loads -> nontemporal; out_rec store ->
// nontemporal. W_rec side loads stay plain (possible L2 hits from stage 1).
#define ITERS 8
#define RESIT 6                                  // iterations with plain prune loads
#define ESTRIDE (8192 * 16)                      // elements advanced per iter
__global__ __launch_bounds__(256) void policy_update(
    const float* __restrict__ pW2, const float* __restrict__ pb2,
    const float* __restrict__ W_rec, const float* __restrict__ h,
    float* __restrict__ out_rec) {
    int lane = threadIdx.x & 63;
    int wave = threadIdx.x >> 6;
    int group = lane >> 4;
    int sub = lane & 15;
    int gw = blockIdx.x * 4 + wave;              // global wave id, 8192 total
    f4 hv = ((const f4*)h)[sub];                 // h[4*sub .. 4*sub+3]
    int e0 = gw * 16 + group * 4;                // group's 4 consecutive elems
    const f4* pr = (const f4*)pW2 + (size_t)e0 * 16 + sub;
    const f4* gr = (const f4*)pW2 + ((size_t)NE + e0) * 16 + sub;
    const size_t FSTR = (size_t)ESTRIDE * 16;    // f4 stride per iteration

    // prologue: iteration 0 loads (element m's row is +m*16 f4s)
    f4 pA[4], gA[4];
    #pragma unroll
    for (int m = 0; m < 4; ++m) {
        pA[m] = pr[m * 16];                      // it=0 < RESIT: plain load
        gA[m] = __builtin_nontemporal_load(gr + m * 16);
    }
    f4 bp{}, bg{}, wv{};
    if (sub == 0) {
        bp = __builtin_nontemporal_load((const f4*)(pb2 + e0));
        bg = __builtin_nontemporal_load((const f4*)(pb2 + NE + e0));
        wv = *(const f4*)(W_rec + e0);
    }

    for (int it = 0; it < ITERS; ++it) {
        // issue NEXT iteration's loads first (stay in flight during compute)
        f4 pN[4] = {}, gN[4] = {};
        f4 bpn{}, bgn{}, wvn{};
        if (it + 1 < ITERS) {
            const f4* prn = pr + (size_t)(it + 1) * FSTR;
            const f4* grn = gr + (size_t)(it + 1) * FSTR;
            if (it + 1 < RESIT) {                // wave-uniform scalar branch
                #pragma unroll
                for (int m = 0; m < 4; ++m) {
                    pN[m] = prn[m * 16];         // plain prune slice (r7 cfg)
                    gN[m] = __builtin_nontemporal_load(grn + m * 16);
                }
            } else {
                #pragma unroll
                for (int m = 0; m < 4; ++m) {
                    pN[m] = __builtin_nontemporal_load(prn + m * 16);
                    gN[m] = __builtin_nontemporal_load(grn + m * 16);
                }
            }
            if (sub == 0) {
                int en = e0 + (it + 1) * ESTRIDE;
                bpn = __builtin_nontemporal_load((const f4*)(pb2 + en));
                bgn = __builtin_nontemporal_load((const f4*)(pb2 + NE + en));
                wvn = *(const f4*)(W_rec + en);
            }
        }
        // compute current iteration: 8 dot-fragments, 8 parallel reductions
        float sp[4], sg[4];
        #pragma unroll
        for (int m = 0; m < 4; ++m) {
            sp[m] = pA[m].x * hv.x + pA[m].y * hv.y + pA[m].z * hv.z + pA[m].w * hv.w;
            sg[m] = gA[m].x * hv.x + gA[m].y * hv.y + gA[m].z * hv.z + gA[m].w * hv.w;
        }
        #pragma unroll
        for (int off = 1; off < 16; off <<= 1) {
            #pragma unroll
            for (int m = 0; m < 4; ++m) {
                sp[m] += __shfl_xor(sp[m], off);
                sg[m] += __shfl_xor(sg[m], off);
            }
        }
        if (sub == 0) {
            int e = e0 + it * ESTRIDE;
            f4 res;
            #pragma unroll
            for (int m = 0; m < 4; ++m) {
                float sig_p = 1.f / (1.f + __expf(-(sp[m] + bp[m])));
                float sig_g = 1.f / (1.f + __expf(-(sg[m] + bg[m])));
                float nw = fmaxf(wv[m] - LR * sig_p + LR * sig_g, 0.f);
                int em = e + m;
                int r = em >> 10, c = em & (N - 1);
                res[m] = (r == c) ? 0.f : nw;
            }
            __builtin_nontemporal_store(res, (f4*)(out_rec + e));
        }
        #pragma unroll
        for (int m = 0; m < 4; ++m) { pA[m] = pN[m]; gA[m] = gN[m]; }
        bp = bpn; bg = bgn; wv = wvn;
    }
}

extern "C" void kernel_launch(void* const* d_in, const int* in_sizes, int n_in,
                              void* d_out, int out_size, void* d_ws, size_t ws_size,
                              hipStream_t stream) {
    const float* in_spk    = (const float*)d_in[0];
    const float* prev_spk  = (const float*)d_in[1];
    const float* potential = (const float*)d_in[2];
    const float* W_in      = (const float*)d_in[3];
    const float* W_rec     = (const float*)d_in[4];
    const float* pW1       = (const float*)d_in[5];
    const float* pb1       = (const float*)d_in[6];
    const float* pW2       = (const float*)d_in[7];
    const float* pb2       = (const float*)d_in[8];
    float* out = (float*)d_out;                  // [0,1024): spikes, then W_rec
    float* ws  = (float*)d_ws;
    float* partial = ws;                         // 64*1024 floats
    float* h       = ws + CHUNKS * N;            // 64 floats (16B-aligned)

    lif_partial<<<256, 256, 0, stream>>>(in_spk, prev_spk, W_in, W_rec, partial);
    finish_mlp1<<<64, 256, 0, stream>>>(partial, potential, prev_spk, pW1, pb1, out, h);
    policy_update<<<2048, 256, 0, stream>>>(pW2, pb2, W_rec, h, out + N);
}